// Round 1
// baseline (893.715 us; speedup 1.0000x reference)
//
#include <hip/hip_runtime.h>

// Problem constants (fixed by the reference: B=16, T=1280000, C=4, su=50, du=640)
// gcd=10 -> up=5, down=64; half_len=640; n_pre_pad=64; K=1345; n_pre_remove=11
// n_out = 100000 = 5 * 20000
#define T_IN   1280000
#define B_N    16
#define N_OUT  100000
#define KH     1345
#define NK     321      // inner-loop steps: m0 = 5k-256 covers all taps, j = 64q+192-k
#define NQ     20000    // q range; outputs n = 5q + r, r in [0,5)
#define NWAVES 5000     // 4 q per wave (16 b x 4 q lanes)

// d_ws layout: hA = float4[NK] (taps r=0..3), hB = float[NK] (tap r=4), zero-padded.
__global__ void build_tables(const float* __restrict__ h, float* __restrict__ ws) {
    int k = blockIdx.x * blockDim.x + threadIdx.x;
    if (k >= NK) return;
    int m0 = 5 * k - 256;
    float4* hA = (float4*)ws;
    float*  hB = ws + NK * 4;
    float v0 = (m0       >= 0 && m0       < KH) ? h[m0]       : 0.0f;
    float v1 = (m0 + 64  >= 0 && m0 + 64  < KH) ? h[m0 + 64]  : 0.0f;
    float v2 = (m0 + 128 >= 0 && m0 + 128 < KH) ? h[m0 + 128] : 0.0f;
    float v3 = (m0 + 192 >= 0 && m0 + 192 < KH) ? h[m0 + 192] : 0.0f;
    float v4 = (m0 + 256 >= 0 && m0 + 256 < KH) ? h[m0 + 256] : 0.0f;
    hA[k] = make_float4(v0, v1, v2, v3);
    hB[k] = v4;
}

#define ACC4(A, HS)                      \
    A.x = fmaf(HS, xv.x, A.x);           \
    A.y = fmaf(HS, xv.y, A.y);           \
    A.z = fmaf(HS, xv.z, A.z);           \
    A.w = fmaf(HS, xv.w, A.w);

__launch_bounds__(256)
__global__ void downsample_poly(const float* __restrict__ x,
                                const float* __restrict__ ws,
                                float* __restrict__ out) {
    const float4* __restrict__ hA = (const float4*)ws;
    const float*  __restrict__ hB = ws + NK * 4;

    int tid  = threadIdx.x;
    int lane = tid & 63;
    int w    = blockIdx.x * 4 + (tid >> 6);   // global wave id, 0..4999
    int qi   = lane & 3;
    int b    = lane >> 2;                      // 16 batches
    int q    = w * 4 + qi;                     // 0..19999

    const float4* __restrict__ xb = (const float4*)x + (size_t)b * T_IN; // x[b][j][0..3]
    int j0 = 64 * q + 192;                     // j = j0 - k, k = 0..320

    float4 a0 = make_float4(0.f, 0.f, 0.f, 0.f);
    float4 a1 = a0, a2 = a0, a3 = a0, a4 = a0;

    // waves 1..4998 never touch j<0 or j>=T (q in [4,19995] -> j in [128,1279872])
    bool safe = (w >= 1) && (w <= 4998);
    if (safe) {
        const float4* __restrict__ p = xb + j0;
        #pragma unroll 4
        for (int k = 0; k < NK; ++k) {
            float4 xv = p[-k];
            float4 ha = hA[k];
            float  hb = hB[k];
            ACC4(a0, ha.x)
            ACC4(a1, ha.y)
            ACC4(a2, ha.z)
            ACC4(a3, ha.w)
            ACC4(a4, hb)
        }
    } else {
        for (int k = 0; k < NK; ++k) {
            int j = j0 - k;
            float4 xv = make_float4(0.f, 0.f, 0.f, 0.f);
            if ((unsigned)j < (unsigned)T_IN) xv = xb[j];
            float4 ha = hA[k];
            float  hb = hB[k];
            ACC4(a0, ha.x)
            ACC4(a1, ha.y)
            ACC4(a2, ha.z)
            ACC4(a3, ha.w)
            ACC4(a4, hb)
        }
    }

    // outputs n = 5q+r, rows are float4 (4 channels)
    float4* __restrict__ o = (float4*)out + ((size_t)b * N_OUT + 5 * (size_t)q);
    o[0] = a0; o[1] = a1; o[2] = a2; o[3] = a3; o[4] = a4;
}

extern "C" void kernel_launch(void* const* d_in, const int* in_sizes, int n_in,
                              void* d_out, int out_size, void* d_ws, size_t ws_size,
                              hipStream_t stream) {
    const float* x = (const float*)d_in[0];
    const float* h = (const float*)d_in[1];
    float* out = (float*)d_out;
    float* ws  = (float*)d_ws;

    // Build zero-padded polyphase tap tables (re-run every launch; d_ws is re-poisoned).
    hipLaunchKernelGGL(build_tables, dim3(2), dim3(192), 0, stream, h, ws);
    // 5000 waves = 1250 blocks x 4 waves; each wave: 16 b x 4 q; each thread: 5 phases x 4 ch.
    hipLaunchKernelGGL(downsample_poly, dim3(1250), dim3(256), 0, stream, x, ws, out);
}

// Round 2
// 492.513 us; speedup vs baseline: 1.8146x; 1.8146x over previous
//
#include <hip/hip_runtime.h>

// B=16, T=1280000, C=4, up=5, down=64, K=1345, n_pre_remove=11, n_out=100000
// Identity (verified round 1): out[b,5q+r,c] = sum_{k=0}^{320} tab[k][r] * x[b, 64q+192-k, c]
//   tab[k][r] = h[5k-256+64r] (0 if index out of [0,1345))
#define T_IN    1280000
#define N_OUT   100000
#define KH      1345
#define NKP     352              // taps padded to 8 splits x 44 (zeros beyond 320)
#define QT      32               // q per block
#define NTILE   625              // 20000/32
#define LOW_PAD 163              // jlo = 64*q0 - 163  (makes ds_read_b128 16B-aligned)
#define SPAN    2340             // samples staged: [64q0-163, 64q0+2176]
#define NGRAN   585              // SPAN/4 float4-granules per channel plane
#define PLANE_GRAN  621          // 585 + (585>>4) skew slots
#define PLANE_BYTES 9936         // 621*16
#define LDS_BYTES   39744        // 4 planes

// tap tables in d_ws: tab4[NKP] float4 (r=0..3) then tab1[NKP] float (r=4)
__global__ void build_tables(const float* __restrict__ h, float* __restrict__ ws) {
    int k = blockIdx.x * blockDim.x + threadIdx.x;
    if (k >= NKP) return;
    int m0 = 5 * k - 256;
    float4* tab4 = (float4*)ws;
    float*  tab1 = ws + NKP * 4;
    float v0 = (m0       >= 0 && m0       < KH) ? h[m0]       : 0.0f;
    float v1 = (m0 + 64  >= 0 && m0 + 64  < KH) ? h[m0 + 64]  : 0.0f;
    float v2 = (m0 + 128 >= 0 && m0 + 128 < KH) ? h[m0 + 128] : 0.0f;
    float v3 = (m0 + 192 >= 0 && m0 + 192 < KH) ? h[m0 + 192] : 0.0f;
    float v4 = (m0 + 256 >= 0 && m0 + 256 < KH) ? h[m0 + 256] : 0.0f;
    tab4[k] = make_float4(v0, v1, v2, v3);
    tab1[k] = v4;
}

// 20 FMAs: tap T (float4 over phases r=0..3) + TB (r=4) times sample component CMP
#define STEP(T, TB, CMP) \
  a0.x = fmaf(T.x, xq0.CMP, a0.x); a0.y = fmaf(T.x, xq1.CMP, a0.y); \
  a0.z = fmaf(T.x, xq2.CMP, a0.z); a0.w = fmaf(T.x, xq3.CMP, a0.w); \
  a1.x = fmaf(T.y, xq0.CMP, a1.x); a1.y = fmaf(T.y, xq1.CMP, a1.y); \
  a1.z = fmaf(T.y, xq2.CMP, a1.z); a1.w = fmaf(T.y, xq3.CMP, a1.w); \
  a2.x = fmaf(T.z, xq0.CMP, a2.x); a2.y = fmaf(T.z, xq1.CMP, a2.y); \
  a2.z = fmaf(T.z, xq2.CMP, a2.z); a2.w = fmaf(T.z, xq3.CMP, a2.w); \
  a3.x = fmaf(T.w, xq0.CMP, a3.x); a3.y = fmaf(T.w, xq1.CMP, a3.y); \
  a3.z = fmaf(T.w, xq2.CMP, a3.z); a3.w = fmaf(T.w, xq3.CMP, a3.w); \
  a4.x = fmaf(TB,  xq0.CMP, a4.x); a4.y = fmaf(TB,  xq1.CMP, a4.y); \
  a4.z = fmaf(TB,  xq2.CMP, a4.z); a4.w = fmaf(TB,  xq3.CMP, a4.w);

__launch_bounds__(256, 4)
__global__ void downsample_poly(const float* __restrict__ x,
                                const float* __restrict__ ws,
                                float* __restrict__ out) {
    __shared__ __align__(16) unsigned char lds_raw[LDS_BYTES];
    const float4* __restrict__ tab4 = (const float4*)ws;
    const float*  __restrict__ tab1 = ws + NKP * 4;

    const int tid  = threadIdx.x;
    const int tile = blockIdx.x;          // 0..624
    const int b    = blockIdx.y;          // 0..15
    const int q0   = tile * QT;
    const int jlo  = 64 * q0 - LOW_PAD;

    const float4* __restrict__ xb = (const float4*)x + (size_t)b * T_IN;

    // ---- stage SPAN samples -> 4 channel planes (granule-skewed), coalesced global reads
    for (int i = tid; i < SPAN; i += 256) {
        int j = jlo + i;
        float4 v = make_float4(0.f, 0.f, 0.f, 0.f);
        if ((unsigned)j < (unsigned)T_IN) v = xb[j];
        int G    = i >> 2;
        int slot = G + (G >> 4);
        int base = slot * 16 + (i & 3) * 4;
        *(float*)(lds_raw + base)                   = v.x;
        *(float*)(lds_raw + base +     PLANE_BYTES) = v.y;
        *(float*)(lds_raw + base + 2 * PLANE_BYTES) = v.z;
        *(float*)(lds_raw + base + 3 * PLANE_BYTES) = v.w;
    }
    __syncthreads();

    // ---- main: thread = (q = tid&31, k-split s = tid>>5 of 44 taps)
    const int q = tid & 31;
    const int s = tid >> 5;
    float4 a0 = make_float4(0.f,0.f,0.f,0.f), a1 = a0, a2 = a0, a3 = a0, a4 = a0;
    const int k00 = s * 44;
    const int Gb0 = 16 * q + 88 - 11 * s;     // Gb = ((64q + 352 - k0)>>2) = Gb0 - g

    #pragma unroll 2
    for (int g = 0; g < 11; ++g) {
        int k0   = k00 + 4 * g;               // taps k0..k0+3 (tab zero-padded past 320)
        int Gb   = Gb0 - g;
        int slot = Gb + (Gb >> 4);
        // 4 consecutive samples per plane; component i <-> tap k0+3-i
        float4 xq0 = *(const float4*)(lds_raw + slot * 16);
        float4 xq1 = *(const float4*)(lds_raw + slot * 16 +     PLANE_BYTES);
        float4 xq2 = *(const float4*)(lds_raw + slot * 16 + 2 * PLANE_BYTES);
        float4 xq3 = *(const float4*)(lds_raw + slot * 16 + 3 * PLANE_BYTES);
        float4 t0 = tab4[k0], t1 = tab4[k0 + 1], t2 = tab4[k0 + 2], t3 = tab4[k0 + 3];
        float4 u1 = *(const float4*)(tab1 + k0);   // tab1[k0..k0+3], 16B aligned
        STEP(t0, u1.x, w)
        STEP(t1, u1.y, z)
        STEP(t2, u1.z, y)
        STEP(t3, u1.w, x)
    }

    // ---- reduce 8 k-split partials per q (reuse x LDS region)
    __syncthreads();
    {
        float4* pp = (float4*)(lds_raw + tid * 80);   // (s*32+q)*80 + r*16
        pp[0] = a0; pp[1] = a1; pp[2] = a2; pp[3] = a3; pp[4] = a4;
    }
    __syncthreads();
    if (tid < 160) {                                  // tid = qq*5 + r
        float sx = 0.f, sy = 0.f, sz = 0.f, sw = 0.f;
        #pragma unroll
        for (int ss = 0; ss < 8; ++ss) {
            float4 p = *(const float4*)(lds_raw + ss * 2560 + tid * 16);
            sx += p.x; sy += p.y; sz += p.z; sw += p.w;
        }
        ((float4*)out)[(size_t)b * N_OUT + 5 * (size_t)q0 + tid] =
            make_float4(sx, sy, sz, sw);
    }
}

extern "C" void kernel_launch(void* const* d_in, const int* in_sizes, int n_in,
                              void* d_out, int out_size, void* d_ws, size_t ws_size,
                              hipStream_t stream) {
    const float* x = (const float*)d_in[0];
    const float* h = (const float*)d_in[1];
    float* out = (float*)d_out;
    float* ws  = (float*)d_ws;

    hipLaunchKernelGGL(build_tables, dim3(2), dim3(192), 0, stream, h, ws);
    hipLaunchKernelGGL(downsample_poly, dim3(NTILE, 16), dim3(256), 0, stream,
                       x, ws, out);
}

// Round 4
// 458.639 us; speedup vs baseline: 1.9486x; 1.0739x over previous
//
#include <hip/hip_runtime.h>

// B=16, T=1280000, C=4, up=5, down=64, K=1345, n_pre_remove=11, n_out=100000
// Identity (verified rounds 1-2): out[b,5q+r,c] = sum_{k=0}^{320} tab[k][r] * x[b, 64q+192-k, c]
//   tab[k][r] = h[5k-256+64r] (0 if index outside [0,1345))
#define T_IN    1280000
#define N_OUT   100000
#define NQ      20000
#define KH      1345
#define NKP     352              // taps padded: 8 splits x 44 (zeros beyond k=320)
#define QT      64               // q per block (= lanes per wave)
#define NTILE   313              // ceil(20000/64); last tile guards stores
#define LOW_PAD 163              // jlo = 64*q0 - 163 (16B-aligns granules)
#define SPAN    4388             // samples staged per block
#define PLANE_BYTES 18640        // (1097 + 68 skew) granules * 16B
#define LDS_BYTES   74560        // 4 channel planes

// tap tables in d_ws: tab4[NKP] float4 (phases r=0..3) then tab1[NKP] float (r=4)
__global__ void build_tables(const float* __restrict__ h, float* __restrict__ ws) {
    int k = blockIdx.x * blockDim.x + threadIdx.x;
    if (k >= NKP) return;
    int m0 = 5 * k - 256;
    float4* tab4 = (float4*)ws;
    float*  tab1 = ws + NKP * 4;
    float v0 = (m0       >= 0 && m0       < KH) ? h[m0]       : 0.0f;
    float v1 = (m0 + 64  >= 0 && m0 + 64  < KH) ? h[m0 + 64]  : 0.0f;
    float v2 = (m0 + 128 >= 0 && m0 + 128 < KH) ? h[m0 + 128] : 0.0f;
    float v3 = (m0 + 192 >= 0 && m0 + 192 < KH) ? h[m0 + 192] : 0.0f;
    float v4 = (m0 + 256 >= 0 && m0 + 256 < KH) ? h[m0 + 256] : 0.0f;
    tab4[k] = make_float4(v0, v1, v2, v3);
    tab1[k] = v4;
}

// 20 FMAs: tap T (float4 over r=0..3) + TB (r=4), times sample component CMP (one q each)
#define STEP(T, TB, CMP) \
  a0.x = fmaf(T.x, xq0.CMP, a0.x); a0.y = fmaf(T.x, xq1.CMP, a0.y); \
  a0.z = fmaf(T.x, xq2.CMP, a0.z); a0.w = fmaf(T.x, xq3.CMP, a0.w); \
  a1.x = fmaf(T.y, xq0.CMP, a1.x); a1.y = fmaf(T.y, xq1.CMP, a1.y); \
  a1.z = fmaf(T.y, xq2.CMP, a1.z); a1.w = fmaf(T.y, xq3.CMP, a1.w); \
  a2.x = fmaf(T.z, xq0.CMP, a2.x); a2.y = fmaf(T.z, xq1.CMP, a2.y); \
  a2.z = fmaf(T.z, xq2.CMP, a2.z); a2.w = fmaf(T.z, xq3.CMP, a2.w); \
  a3.x = fmaf(T.w, xq0.CMP, a3.x); a3.y = fmaf(T.w, xq1.CMP, a3.y); \
  a3.z = fmaf(T.w, xq2.CMP, a3.z); a3.w = fmaf(T.w, xq3.CMP, a3.w); \
  a4.x = fmaf(TB,  xq0.CMP, a4.x); a4.y = fmaf(TB,  xq1.CMP, a4.y); \
  a4.z = fmaf(TB,  xq2.CMP, a4.z); a4.w = fmaf(TB,  xq3.CMP, a4.w);

__launch_bounds__(512, 4)
__global__ void downsample_poly(const float* __restrict__ x,
                                const float* __restrict__ ws,
                                float* __restrict__ out) {
    extern __shared__ __align__(16) unsigned char lds_raw[];
    const int tid = threadIdx.x;
    const int b   = blockIdx.y;
    const int q0  = blockIdx.x * QT;
    const int jlo = 64 * q0 - LOW_PAD;

    const float4* __restrict__ xb = (const float4*)x + (size_t)b * T_IN;

    // ---- stage SPAN samples -> 4 skewed channel planes (coalesced float4 reads)
    for (int i = tid; i < SPAN; i += 512) {
        int j = jlo + i;
        float4 v = make_float4(0.f, 0.f, 0.f, 0.f);
        if ((unsigned)j < (unsigned)T_IN) v = xb[j];
        int G    = i >> 2;
        int slot = G + (G >> 4);
        int base = slot * 16 + (i & 3) * 4;
        *(float*)(lds_raw + base)                   = v.x;
        *(float*)(lds_raw + base +     PLANE_BYTES) = v.y;
        *(float*)(lds_raw + base + 2 * PLANE_BYTES) = v.z;
        *(float*)(lds_raw + base + 3 * PLANE_BYTES) = v.w;
    }
    __syncthreads();

    // ---- main: lane = q (dq 0..63), wave = tap split s (0..7, 44 taps each)
    const int dq = tid & 63;
    const int su = __builtin_amdgcn_readfirstlane(tid >> 6);  // wave-uniform -> SGPR
    const float4* __restrict__ tap4 = (const float4*)ws;
    const float*  __restrict__ tap1 = ws + NKP * 4;

    float4 a0 = make_float4(0.f,0.f,0.f,0.f), a1 = a0, a2 = a0, a3 = a0, a4 = a0;
    const int k00 = su * 44;
    const int Gb0 = 16 * dq + 88 - 11 * su;    // granule of taps k0..k0+3

    #pragma unroll 2
    for (int g = 0; g < 11; ++g) {
        int k0   = k00 + 4 * g;                // tab zero-padded past k=320
        int Gb   = Gb0 - g;
        int slot = Gb + (Gb >> 4);
        const unsigned char* pb = lds_raw + slot * 16;
        // 4 consecutive samples per plane; component i <-> tap k0+3-i
        float4 xq0 = *(const float4*)(pb);
        float4 xq1 = *(const float4*)(pb +     PLANE_BYTES);
        float4 xq2 = *(const float4*)(pb + 2 * PLANE_BYTES);
        float4 xq3 = *(const float4*)(pb + 3 * PLANE_BYTES);
        // wave-uniform tap addresses -> scalar loads
        float4 t0 = tap4[k0], t1 = tap4[k0 + 1], t2 = tap4[k0 + 2], t3 = tap4[k0 + 3];
        float4 u1 = *(const float4*)(tap1 + k0);
        STEP(t0, u1.x, w)
        STEP(t1, u1.y, z)
        STEP(t2, u1.z, y)
        STEP(t3, u1.w, x)
    }

    // ---- reduce 8 wave-partials per (q, r) through LDS
    __syncthreads();
    {
        float4* pp = (float4*)(lds_raw + tid * 80);   // (s*64+dq)*80 + r*16
        pp[0] = a0; pp[1] = a1; pp[2] = a2; pp[3] = a3; pp[4] = a4;
    }
    __syncthreads();
    if (tid < 320 && 5 * q0 + tid < 5 * NQ) {         // tid = qq*5 + r
        float sx = 0.f, sy = 0.f, sz = 0.f, sw = 0.f;
        #pragma unroll
        for (int ss = 0; ss < 8; ++ss) {
            float4 p = *(const float4*)(lds_raw + ss * 5120 + tid * 16);
            sx += p.x; sy += p.y; sz += p.z; sw += p.w;
        }
        ((float4*)out)[(size_t)b * N_OUT + 5 * (size_t)q0 + tid] =
            make_float4(sx, sy, sz, sw);
    }
}

extern "C" void kernel_launch(void* const* d_in, const int* in_sizes, int n_in,
                              void* d_out, int out_size, void* d_ws, size_t ws_size,
                              hipStream_t stream) {
    const float* x = (const float*)d_in[0];
    const float* h = (const float*)d_in[1];
    float* out = (float*)d_out;
    float* ws  = (float*)d_ws;

    // allow 74.5 KB dynamic LDS (host-side attribute set; not a stream op,
    // safe under graph capture; idempotent every call)
    hipFuncSetAttribute((const void*)downsample_poly,
                        hipFuncAttributeMaxDynamicSharedMemorySize, LDS_BYTES);

    hipLaunchKernelGGL(build_tables, dim3(2), dim3(192), 0, stream, h, ws);
    hipLaunchKernelGGL(downsample_poly, dim3(NTILE, 16), dim3(512), LDS_BYTES,
                       stream, x, ws, out);
}

// Round 6
// 449.544 us; speedup vs baseline: 1.9880x; 1.0202x over previous
//
#include <hip/hip_runtime.h>

// B=16, T=1280000, C=4, up=5, down=64, K=1345, n_pre_remove=11, n_out=100000
// Identity (verified rounds 1-4): out[b,5q+r,c] = sum_{k=0}^{320} tab[k][r] * x[b, 64q+192-k, c]
//   tab[k][r] = h[5k-256+64r] (0 if index outside [0,1345)); taps padded to 352 (8 splits x 44)
// f16 channel-plane LDS + v_dot2_f32_f16, XOR bank swizzle, 40KB/block -> 4 blocks/CU.
typedef _Float16 h2 __attribute__((ext_vector_type(2)));
typedef _Float16 h4 __attribute__((ext_vector_type(4)));

#define T_IN   1280000
#define N_OUT  100000
#define NQ     20000
#define KH     1345
#define NMP    176        // f16 tap pairs per phase r (352 taps / 2)
#define QT     64         // q per block; lane = dq, wave = tap split s (uniform)
#define NTILE  313        // ceil(20000/64)
#define OFFJ   159        // jlo = 64*q0 - 159; sample i = 64*dq + 351 - k  (k up to 351 padded)
#define NPAIR  2240       // staged sample PAIRS (samples 0..4479 >= max read 4383)
#define PLANE  9216       // bytes per f16 channel plane (incl. swizzle headroom)
#define SWZ(b) ((b) ^ ((((b) >> 7) & 15) << 3))   // spreads 128B-stride lanes over 32 banks
#define PKRTZ(a, b) __builtin_bit_cast(h2, __builtin_amdgcn_cvt_pkrtz((a), (b)))

// ws: tap pair table, u32-packed half2: ws[m*5+r] = (tap[2m+1], tap[2m]) for phase r.
// Pair order matches descending-k sample order: low half2 of a b64 read multiplies entry m0+1.
__global__ void build_tables(const float* __restrict__ h, unsigned* __restrict__ ws) {
    int m = blockIdx.x * blockDim.x + threadIdx.x;
    if (m >= NMP) return;
    #pragma unroll
    for (int r = 0; r < 5; ++r) {
        int ilo = 5 * (2 * m)     - 256 + 64 * r;
        int ihi = 5 * (2 * m + 1) - 256 + 64 * r;
        float vlo = (ilo >= 0 && ilo < KH) ? h[ilo] : 0.f;
        float vhi = (ihi >= 0 && ihi < KH) ? h[ihi] : 0.f;
        h2 p = PKRTZ(vhi, vlo);   // elem0 = tap(2m+1), elem1 = tap(2m)
        ws[m * 5 + r] = __builtin_bit_cast(unsigned, p);
    }
}

// per phase r: acc.c += dot2(thi, low-pair_c) + dot2(tlo, high-pair_c)
#define DOT_R(AR, TH, TL) \
  AR.x = __builtin_amdgcn_fdot2(TH, Xl0, AR.x, false); \
  AR.x = __builtin_amdgcn_fdot2(TL, Xh0, AR.x, false); \
  AR.y = __builtin_amdgcn_fdot2(TH, Xl1, AR.y, false); \
  AR.y = __builtin_amdgcn_fdot2(TL, Xh1, AR.y, false); \
  AR.z = __builtin_amdgcn_fdot2(TH, Xl2, AR.z, false); \
  AR.z = __builtin_amdgcn_fdot2(TL, Xh2, AR.z, false); \
  AR.w = __builtin_amdgcn_fdot2(TH, Xl3, AR.w, false); \
  AR.w = __builtin_amdgcn_fdot2(TL, Xh3, AR.w, false);

__launch_bounds__(512, 8)
__global__ void downsample_poly(const float* __restrict__ x,
                                const unsigned* __restrict__ ws,
                                float* __restrict__ out) {
    __shared__ __align__(16) char lds[40960];   // 4 planes (36864) < reduce buf (40960)
    const int tid = threadIdx.x;
    const int b   = blockIdx.y;
    const int q0  = blockIdx.x * QT;
    const int jlo = 64 * q0 - OFFJ;
    const float4* __restrict__ xb = (const float4*)x + (size_t)b * T_IN;

    // ---- stage: fp32 HBM -> f16 channel planes (pairs along time), swizzled
    #pragma unroll
    for (int it = 0; it < 5; ++it) {
        int i2 = tid + it * 512;
        if (i2 < NPAIR) {
            int j0 = jlo + 2 * i2;
            float4 v0 = make_float4(0.f, 0.f, 0.f, 0.f), v1 = v0;
            if ((unsigned)j0       < (unsigned)T_IN) v0 = xb[j0];
            if ((unsigned)(j0 + 1) < (unsigned)T_IN) v1 = xb[j0 + 1];
            int bb = SWZ(4 * i2);
            *(h2*)(lds + bb)             = PKRTZ(v0.x, v1.x);
            *(h2*)(lds + bb +     PLANE) = PKRTZ(v0.y, v1.y);
            *(h2*)(lds + bb + 2 * PLANE) = PKRTZ(v0.z, v1.z);
            *(h2*)(lds + bb + 3 * PLANE) = PKRTZ(v0.w, v1.w);
        }
    }
    __syncthreads();

    // ---- main: lane = dq (0..63), wave = split su (0..7, 44 taps each)
    const int dq = tid & 63;
    const int su = __builtin_amdgcn_readfirstlane(tid >> 6);
    float4 a0 = make_float4(0.f,0.f,0.f,0.f), a1 = a0, a2 = a0, a3 = a0, a4 = a0;
    const int rb0 = 128 * dq + 696 - 88 * su;   // byte = 2*i_lo, i_lo = 64dq+348-k0

    #pragma unroll 2
    for (int g = 0; g < 11; ++g) {
        int sw = SWZ(rb0 - 8 * g);
        h4 X0 = *(const h4*)(lds + sw);
        h4 X1 = *(const h4*)(lds + sw +     PLANE);
        h4 X2 = *(const h4*)(lds + sw + 2 * PLANE);
        h4 X3 = *(const h4*)(lds + sw + 3 * PLANE);
        h2 Xl0 = {X0[0], X0[1]}, Xh0 = {X0[2], X0[3]};
        h2 Xl1 = {X1[0], X1[1]}, Xh1 = {X1[2], X1[3]};
        h2 Xl2 = {X2[0], X2[1]}, Xh2 = {X2[2], X2[3]};
        h2 Xl3 = {X3[0], X3[1]}, Xh3 = {X3[2], X3[3]};
        const unsigned* tw = ws + (110 * su + 10 * g);   // wave-uniform -> s_load
        h2 th, tl;
        th = __builtin_bit_cast(h2, tw[5]); tl = __builtin_bit_cast(h2, tw[0]); DOT_R(a0, th, tl)
        th = __builtin_bit_cast(h2, tw[6]); tl = __builtin_bit_cast(h2, tw[1]); DOT_R(a1, th, tl)
        th = __builtin_bit_cast(h2, tw[7]); tl = __builtin_bit_cast(h2, tw[2]); DOT_R(a2, th, tl)
        th = __builtin_bit_cast(h2, tw[8]); tl = __builtin_bit_cast(h2, tw[3]); DOT_R(a3, th, tl)
        th = __builtin_bit_cast(h2, tw[9]); tl = __builtin_bit_cast(h2, tw[4]); DOT_R(a4, th, tl)
    }

    // ---- reduce 8 wave-partials per (q, r) through LDS (validated round 4)
    __syncthreads();
    {
        float4* pp = (float4*)(lds + tid * 80);
        pp[0] = a0; pp[1] = a1; pp[2] = a2; pp[3] = a3; pp[4] = a4;
    }
    __syncthreads();
    if (tid < 320 && 5 * q0 + tid < 5 * NQ) {            // tid = qq*5 + r
        float sx = 0.f, sy = 0.f, sz = 0.f, sw2 = 0.f;
        #pragma unroll
        for (int ss = 0; ss < 8; ++ss) {
            float4 p = *(const float4*)(lds + ss * 5120 + tid * 16);
            sx += p.x; sy += p.y; sz += p.z; sw2 += p.w;
        }
        ((float4*)out)[(size_t)b * N_OUT + 5 * (size_t)q0 + tid] =
            make_float4(sx, sy, sz, sw2);
    }
}

extern "C" void kernel_launch(void* const* d_in, const int* in_sizes, int n_in,
                              void* d_out, int out_size, void* d_ws, size_t ws_size,
                              hipStream_t stream) {
    const float* x = (const float*)d_in[0];
    const float* h = (const float*)d_in[1];
    float* out = (float*)d_out;
    unsigned* ws = (unsigned*)d_ws;

    hipLaunchKernelGGL(build_tables, dim3(1), dim3(192), 0, stream, h, ws);
    hipLaunchKernelGGL(downsample_poly, dim3(NTILE, 16), dim3(512), 0, stream,
                       x, ws, out);
}